// Round 7
// baseline (230.161 us; speedup 1.0000x reference)
//
#include <hip/hip_runtime.h>
#include <hip/hip_bf16.h>

typedef short bf16x8 __attribute__((ext_vector_type(8)));
typedef short short4v __attribute__((ext_vector_type(4)));
typedef float f32x4 __attribute__((ext_vector_type(4)));
typedef float f32x16 __attribute__((ext_vector_type(16)));

template <bool V> struct BoolC { static constexpr bool value = V; };

__device__ __forceinline__ short f2b(float f) {
  __hip_bfloat16 h = __float2bfloat16(f);
  union { __hip_bfloat16 h; short s; } u; u.h = h; return u.s;
}

// packed f32->bf16 pair (RNE), low = lo, high = hi
__device__ __forceinline__ unsigned cvtpk_bf16(float lo, float hi) {
  unsigned r;
  asm("v_cvt_pk_bf16_f32 %0, %1, %2" : "=v"(r) : "v"(lo), "v"(hi));
  return r;
}

__device__ __forceinline__ f32x16 mfma32(bf16x8 a, bf16x8 b, f32x16 c) {
  return __builtin_amdgcn_mfma_f32_32x32x16_bf16(a, b, c, 0, 0, 0);
}

// async 16B global -> LDS DMA (lane i lands at lds_base + i*16; lds ptr wave-uniform)
__device__ __forceinline__ void async_copy16(const short* g, short* l) {
  __builtin_amdgcn_global_load_lds((const __attribute__((address_space(1))) void*)g,
                                   (__attribute__((address_space(3))) void*)l, 16, 0, 0);
}

// ---------------- fused preprocessing: x->bf16, w_attn^T (qscaled), w_proj^T ----------------
__global__ __launch_bounds__(256) void pre_kernel(const float* __restrict__ x, short* __restrict__ xb,
                                                  const float* __restrict__ wa, short* __restrict__ waT,
                                                  const float* __restrict__ wp, short* __restrict__ wpT,
                                                  float qscale) {
  const int tid = threadIdx.x;
  const int blk = blockIdx.x;
  if (blk < 8192) {
    const int i = blk * 256 + tid;
    const float4 v = ((const float4*)x)[i];
    short4v o;
    o[0] = f2b(v.x); o[1] = f2b(v.y); o[2] = f2b(v.z); o[3] = f2b(v.w);
    ((short4v*)xb)[i] = o;
    return;
  }
  __shared__ float t[32][33];
  const float* in; short* out;
  int idx, gxb, Cn, qrows; float qs;
  if (blk < 11264) { idx = blk - 8192;  in = wa; out = waT; gxb = 96; Cn = 3072; qrows = 1024; qs = qscale; }
  else             { idx = blk - 11264; in = wp; out = wpT; gxb = 32; Cn = 1024; qrows = 0;    qs = 1.0f; }
  const int bx = idx % gxb, by = idx / gxb;
  const int tx = tid & 31, ty = tid >> 5;
  const int c0 = bx * 32, r0 = by * 32;
#pragma unroll
  for (int yy = 0; yy < 32; yy += 8)
    t[ty + yy][tx] = in[(size_t)(r0 + ty + yy) * Cn + (c0 + tx)];
  __syncthreads();
#pragma unroll
  for (int yy = 0; yy < 32; yy += 8) {
    const int orow = c0 + ty + yy;
    float v = t[tx][ty + yy];
    if (orow < qrows) v *= qs;
    out[(size_t)orow * 1024 + (r0 + tx)] = f2b(v);
  }
}

// ---------------- C = A * Bt^T — high-occupancy GEMM: 128xBN tile, BK=32, 16 waves/CU ----------------
// 512 threads = 8 waves (2M x 4N; wave tile 64 x BN/4). Double-buffered LDS is only
// (8 + BN/16) KB/buf -> 40 KB (BN=192) / 32 KB (BN=128); VGPR <= 128 via launch_bounds(512,4)
// -> 2 blocks x 8 waves = 16 waves/CU = 4 waves/SIMD. This doubles TLP vs the 4-phase design:
// R6 counters showed per-SIMD MFMA duty ~10% with everything idle at 8 waves/CU — the period
// was serial latency chains (guard -> barrier -> ds_read -> MFMA), coverable only by more waves.
// ONE barrier + ONE vmcnt(0) per K-tile(32): each wave drains its OWN 2-3 DMA loads (issued a
// full tile-period earlier = ~1800 cyc lead >> 900 cyc HBM latency) BEFORE the barrier, so after
// the barrier ALL waves' loads are visible — no vmcnt ledger needed. 32 sync points (vs 64).
// XOR chunk swizzle: LDS[r][p] holds global chunk p ^ s(r), s(r) = (r ^ r>>2) & 3 — base-16
// independent, so DMA (16 rows/instr) and frag reads use the same s of their local row index;
// frag-read banks = 2 lanes/bank-group = free. DMA dest stays linear (required).
// VFUSE (qkv only): cols<2048 -> qk[row][2048]; cols>=2048 -> V stored transposed into vT.
template <int BN, typename OutT, bool VFUSE>
__global__ __launch_bounds__(512, 4) void gemm_hi_kernel(const short* __restrict__ A,
                                                         const short* __restrict__ Bt,
                                                         OutT* __restrict__ C,
                                                         short* __restrict__ vTo,
                                                         int M, int N, int K) {
  constexpr int NB = BN / 64;          // n-frags per wave (3 or 2)
  constexpr int NBU = BN / 16;         // B stage units (16 rows x 32k = 1KB each)
  constexpr int U = NBU + 8;           // + 8 A units
  constexpr int BSHORT = (8 + NBU) * 512;  // shorts per buffer (A at 0, B at 4096)
  __shared__ short lds[2][BSHORT];

  const int tid = threadIdx.x;
  const int w = tid >> 6, lane = tid & 63;
  const int quad = lane >> 4, l16 = lane & 15;
  const int mh = w >> 2;               // m-half 0/1
  const int wn = (w & 3) * (BN / 4);   // n-slice base

  // XCD-aware bijective swizzle (grid divisible by 8)
  const int gx = gridDim.x;
  const int nwg = gx * gridDim.y;
  const int flat = blockIdx.y * gx + blockIdx.x;
  const int swz = (flat & 7) * (nwg >> 3) + (flat >> 3);
  const int bn = swz % gx, bm = swz / gx;
  const int m0 = bm * 128, n0 = bn * BN;

  // staging: DMA instr covers 16 rows x 64B; lane -> row r16=lane>>2, phys chunk pc=lane&3,
  // fetching global logical chunk pc ^ s(r16)  (inverse swizzle; involution)
  const int r16 = lane >> 2, pc = lane & 3;
  const int cl = pc ^ ((r16 ^ (r16 >> 2)) & 3);
  const int us = (w * U) >> 3, ue = ((w + 1) * U) >> 3;
  const int nu = ue - us;              // 2 or 3 units per wave
  const short* gsrc[3];
  int loff[3];
#pragma unroll
  for (int i = 0; i < 3; ++i) {
    const int u = us + i;
    if (i < nu) {
      if (u < NBU) { gsrc[i] = Bt + (size_t)(n0 + u * 16 + r16) * K + cl * 8; loff[i] = 4096 + u * 512; }
      else { const int a = u - NBU; gsrc[i] = A + (size_t)(m0 + a * 16 + r16) * K + cl * 8; loff[i] = a * 512; }
    } else { gsrc[i] = Bt; loff[i] = 0; }
  }

  f32x4 acc[4][NB] = {};
  const int s16 = (l16 ^ (l16 >> 2)) & 3;  // frag-read swizzle of this lane's row

  auto stage = [&](int buf, int t) {
#pragma unroll
    for (int i = 0; i < 3; ++i)
      if (i < nu) async_copy16(gsrc[i] + t * 32, &lds[buf][loff[i]]);
  };

  stage(0, 0);  // prologue: tile 0 -> buf 0

  const int NT = K >> 5;  // 32 K-tiles
  for (int t = 0; t < NT; ++t) {
    const int buf = t & 1;
    // own ds_reads retired (cross-buffer DMA-write hazard), own DMAs landed; then barrier
    // makes ALL waves' tile-t loads visible.
    asm volatile("s_waitcnt lgkmcnt(0)" ::: "memory");
    asm volatile("s_waitcnt vmcnt(0)" ::: "memory");
    __builtin_amdgcn_s_barrier();
    asm volatile("" ::: "memory");
    if (t + 1 < NT) stage(buf ^ 1, t + 1);  // full-tile prefetch lead
    bf16x8 af[4], bf[NB];
#pragma unroll
    for (int mf = 0; mf < 4; ++mf)
      af[mf] = *(const bf16x8*)&lds[buf][(mh * 64 + mf * 16 + l16) * 32 + ((quad ^ s16) * 8)];
#pragma unroll
    for (int nf = 0; nf < NB; ++nf)
      bf[nf] = *(const bf16x8*)&lds[buf][4096 + (wn + nf * 16 + l16) * 32 + ((quad ^ s16) * 8)];
    __builtin_amdgcn_s_setprio(1);
#pragma unroll
    for (int mf = 0; mf < 4; ++mf)
#pragma unroll
      for (int nf = 0; nf < NB; ++nf)
        acc[mf][nf] = __builtin_amdgcn_mfma_f32_16x16x32_bf16(af[mf], bf[nf], acc[mf][nf], 0, 0, 0);
    __builtin_amdgcn_s_setprio(0);
  }

  (void)M;
#pragma unroll
  for (int mf = 0; mf < 4; ++mf)
#pragma unroll
    for (int nf = 0; nf < NB; ++nf) {
      const int col = n0 + wn + nf * 16 + l16;
      const int row0 = m0 + mh * 64 + mf * 16 + quad * 4;
      if constexpr (VFUSE) {
        if (col < 2048) {  // Q,K -> qk buffer, row stride 2048 (uniform per nf iteration)
#pragma unroll
          for (int r = 0; r < 4; ++r)
            C[(size_t)(row0 + r) * 2048 + col] = f2b(acc[mf][nf][r]);
        } else {           // V -> transposed vT[(b*16+h)*64+d][t], aligned 8B store
          const int dp = col - 2048;
          const int bh64 = ((row0 >> 11) * 16 + (dp >> 6)) * 64 + (dp & 63);
          const int t0 = row0 & 2047;
          short4v v4;
#pragma unroll
          for (int r = 0; r < 4; ++r) v4[r] = f2b(acc[mf][nf][r]);
          *(short4v*)&vTo[(size_t)bh64 * 2048 + t0] = v4;
        }
      } else {
#pragma unroll
        for (int r = 0; r < 4; ++r) {
          const int row = row0 + r;
          if constexpr (sizeof(OutT) == 4)
            C[(size_t)row * N + col] = acc[mf][nf][r];
          else
            C[(size_t)row * N + col] = f2b(acc[mf][nf][r]);
        }
      }
    }
}

// ---------------- causal flash attention: 32x32 swapped-QK^T, in-register softmax ----------------
// R4-proven structure: grid (8, B*H) XCD-remapped (8 heads/XCD share K/V in L2); block =
// 4 waves x 32 q-rows = 128-row qtile; block xb handles qtiles {15-xb, xb} (balanced 36 iters).
// S^T = mfma32(K, Q): col=q=lane&31, each lane owns a full P row slice in regs. exp2 in place;
// P->bf16 A-frags via v_cvt_pk_bf16_f32 + v_permlane32_swap_b32 (no LDS round-trip). l via
// ones-MFMA (C-layout). K/V LDS XOR-chunk-swizzled via permuted DMA source addrs (dest linear).
// Waves skip fully-masked tiles (j>jd) and the masked upper-kv half (up guard).
__global__ __launch_bounds__(256, 2) void attn_kernel(const short* __restrict__ qk,
                                                      const short* __restrict__ vT,
                                                      short* __restrict__ y) {
  constexpr int T = 2048, C2 = 2048, Cc = 1024, HD = 64;
  const int f = blockIdx.y * 8 + blockIdx.x;
  const int bh = (f & 7) * 8 + ((f >> 3) & 7);
  const int xb = f >> 6;
  const int b = bh >> 4, h = bh & 15;
  const int tid = threadIdx.x, lane = tid & 63, wave = tid >> 6;
  const int l32 = lane & 31, hi = lane >> 5;

  __shared__ short Ksb[2][64 * 64];    // [buf][kv][d], XOR-swizzled 16B chunks
  __shared__ short Vtb[2][64 * 64];    // [buf][d][kv], XOR-swizzled 16B chunks

  const size_t base = (size_t)b * T * C2;
  const int qcol = h * HD, kcol = 1024 + h * HD;
  const size_t vtbase = (size_t)bh * HD * T;

  const int r8 = lane >> 3;
  const int cg8 = ((lane & 7) ^ r8) * 8;
  const short* gk[2];
  const short* gv[2];
  short* lk[2][2]; short* lv[2][2];
#pragma unroll
  for (int t8 = 0; t8 < 2; t8++) {
    const int row = wave * 16 + t8 * 8 + r8;
    gk[t8] = qk + base + (size_t)row * C2 + kcol + cg8;
    gv[t8] = vT + vtbase + (size_t)row * T + cg8;
#pragma unroll
    for (int bu = 0; bu < 2; bu++) {
      lk[bu][t8] = &Ksb[bu][(wave * 16 + t8 * 8) * 64];
      lv[bu][t8] = &Vtb[bu][(wave * 16 + t8 * 8) * 64];
    }
  }
  const int rs7 = l32 & 7;  // frag-read row parity for chunk XOR

  bf16x8 ones;
#pragma unroll
  for (int i = 0; i < 8; i++) ones[i] = (short)0x3F80;  // bf16 1.0

  for (int half = 0; half < 2; half++) {
    const int t = half ? xb : (15 - xb);
    const int q0 = t * 128;
    const int jmax = 2 * t + 1;
    const int jd = 2 * t + (wave >> 1);       // this wave's diagonal KV-tile
    const int qrow = q0 + wave * 32 + l32;    // this lane's q (S^T col)

    bf16x8 qf[4];
    {
      const short* qp = qk + base + (size_t)qrow * C2 + qcol + hi * 8;
#pragma unroll
      for (int wk = 0; wk < 4; wk++) qf[wk] = *(const bf16x8*)(qp + wk * 16);
    }

    f32x16 o0 = {}, o1 = {}, lC = {};

    async_copy16(gk[0], lk[0][0]);
    async_copy16(gk[1], lk[0][1]);
    async_copy16(gv[0], lv[0][0]);
    async_copy16(gv[1], lv[0][1]);

    for (int j = 0; j <= jmax; j++) {
      const int cur = j & 1;
      __syncthreads();  // drains vmcnt: tile j staged in buf[cur]

      if (j < jmax) {
        const size_t ko = (size_t)(j + 1) * 64 * C2;
        const int vo = (j + 1) * 64;
        async_copy16(gk[0] + ko, lk[cur ^ 1][0]);
        async_copy16(gk[1] + ko, lk[cur ^ 1][1]);
        async_copy16(gv[0] + vo, lv[cur ^ 1][0]);
        async_copy16(gv[1] + vo, lv[cur ^ 1][1]);
      }

      if (j > jd) continue;  // fully-masked tile for this wave (barriers above still uniform)

      const bool up = (64 * j + 32) <= (q0 + wave * 32 + 31);

      // ---- QK^T (swapped): st = K-tile x Q^T, col=q, row=kv ----
      f32x16 st0 = {}, st1 = {};
      __builtin_amdgcn_s_setprio(1);
#pragma unroll
      for (int wk = 0; wk < 4; wk++) {
        const bf16x8 k0 = *(const bf16x8*)&Ksb[cur][l32 * 64 + (((2 * wk + hi) ^ rs7) * 8)];
        st0 = mfma32(k0, qf[wk], st0);
      }
      if (up) {
#pragma unroll
        for (int wk = 0; wk < 4; wk++) {
          const bf16x8 k1 = *(const bf16x8*)&Ksb[cur][(32 + l32) * 64 + (((2 * wk + hi) ^ rs7) * 8)];
          st1 = mfma32(k1, qf[wk], st1);
        }
      }
      __builtin_amdgcn_s_setprio(0);

      // ---- causal mask on diagonal tile ----
      if (j == jd) {
#pragma unroll
        for (int r = 0; r < 16; r++) {
          const int kvl = 64 * j + (r & 3) + 8 * (r >> 2) + 4 * hi;
          if (kvl > qrow) st0[r] = -INFINITY;
          if (up && (kvl + 32 > qrow)) st1[r] = -INFINITY;
        }
      }

      // ---- V B-frags (kv-windows 0,1 always; 2,3 only if up) ----
      bf16x8 vf00, vf01, vf10, vf11, vf02, vf03, vf12, vf13;
      vf00 = *(const bf16x8*)&Vtb[cur][l32 * 64 + (((0 + hi) ^ rs7) * 8)];
      vf01 = *(const bf16x8*)&Vtb[cur][l32 * 64 + (((2 + hi) ^ rs7) * 8)];
      vf10 = *(const bf16x8*)&Vtb[cur][(32 + l32) * 64 + (((0 + hi) ^ rs7) * 8)];
      vf11 = *(const bf16x8*)&Vtb[cur][(32 + l32) * 64 + (((2 + hi) ^ rs7) * 8)];
      if (up) {
        vf02 = *(const bf16x8*)&Vtb[cur][l32 * 64 + (((4 + hi) ^ rs7) * 8)];
        vf03 = *(const bf16x8*)&Vtb[cur][l32 * 64 + (((6 + hi) ^ rs7) * 8)];
        vf12 = *(const bf16x8*)&Vtb[cur][(32 + l32) * 64 + (((4 + hi) ^ rs7) * 8)];
        vf13 = *(const bf16x8*)&Vtb[cur][(32 + l32) * 64 + (((6 + hi) ^ rs7) * 8)];
      }

      // ---- exp2 in-place, pack P->bf16 A-frags via cvt_pk + permlane32_swap ----
#pragma unroll
      for (int r = 0; r < 16; r++) st0[r] = __builtin_amdgcn_exp2f(st0[r]);
      bf16x8 pa0, pa1, pa2, pa3;
      {
        unsigned a0 = cvtpk_bf16(st0[0], st0[1]), c0 = cvtpk_bf16(st0[2], st0[3]);
        unsigned b0 = cvtpk_bf16(st0[4], st0[5]), d0 = cvtpk_bf16(st0[6], st0[7]);
        asm volatile("v_permlane32_swap_b32 %0, %1" : "+v"(a0), "+v"(b0));
        asm volatile("v_permlane32_swap_b32 %0, %1" : "+v"(c0), "+v"(d0));
        union { unsigned u[4]; bf16x8 v; } p; p.u[0] = a0; p.u[1] = c0; p.u[2] = b0; p.u[3] = d0;
        pa0 = p.v;
        unsigned a1 = cvtpk_bf16(st0[8], st0[9]), c1 = cvtpk_bf16(st0[10], st0[11]);
        unsigned b1 = cvtpk_bf16(st0[12], st0[13]), d1 = cvtpk_bf16(st0[14], st0[15]);
        asm volatile("v_permlane32_swap_b32 %0, %1" : "+v"(a1), "+v"(b1));
        asm volatile("v_permlane32_swap_b32 %0, %1" : "+v"(c1), "+v"(d1));
        union { unsigned u[4]; bf16x8 v; } q; q.u[0] = a1; q.u[1] = c1; q.u[2] = b1; q.u[3] = d1;
        pa1 = q.v;
      }
      if (up) {
#pragma unroll
        for (int r = 0; r < 16; r++) st1[r] = __builtin_amdgcn_exp2f(st1[r]);
        unsigned a2 = cvtpk_bf16(st1[0], st1[1]), c2 = cvtpk_bf16(st1[2], st1[3]);
        unsigned b2 = cvtpk_bf16(st1[4], st1[5]), d2 = cvtpk_bf16(st1[6], st1[7]);
        asm volatile("v_permlane32_swap_b32 %0, %1" : "+v"(a2), "+v"(b2));
        asm volatile("v_permlane32_swap_b32 %0, %1" : "+v"(c2), "+v"(d2));
        union { unsigned u[4]; bf16x8 v; } p; p.u[0] = a2; p.u[1] = c2; p.u[2] = b2; p.u[3] = d2;
        pa2 = p.v;
        unsigned a3 = cvtpk_bf16(st1[8], st1[9]), c3 = cvtpk_bf16(st1[10], st1[11]);
        unsigned b3 = cvtpk_bf16(st1[12], st1[13]), d3 = cvtpk_bf16(st1[14], st1[15]);
        asm volatile("v_permlane32_swap_b32 %0, %1" : "+v"(a3), "+v"(b3));
        asm volatile("v_permlane32_swap_b32 %0, %1" : "+v"(c3), "+v"(d3));
        union { unsigned u[4]; bf16x8 v; } q; q.u[0] = a3; q.u[1] = c3; q.u[2] = b3; q.u[3] = d3;
        pa3 = q.v;
      }

      // ---- l-sum (ones-MFMA, C-layout) + PV ----
      __builtin_amdgcn_s_setprio(1);
      lC = mfma32(pa0, ones, lC);
      lC = mfma32(pa1, ones, lC);
      o0 = mfma32(pa0, vf00, o0);
      o0 = mfma32(pa1, vf01, o0);
      o1 = mfma32(pa0, vf10, o1);
      o1 = mfma32(pa1, vf11, o1);
      if (up) {
        lC = mfma32(pa2, ones, lC);
        lC = mfma32(pa3, ones, lC);
        o0 = mfma32(pa2, vf02, o0);
        o0 = mfma32(pa3, vf03, o0);
        o1 = mfma32(pa2, vf12, o1);
        o1 = mfma32(pa3, vf13, o1);
      }
      __builtin_amdgcn_s_setprio(0);
    }

    // ---- epilogue: divide by l (same C-layout), store bf16 ----
#pragma unroll
    for (int r = 0; r < 16; r++) {
      const int rq = (r & 3) + 8 * (r >> 2) + 4 * hi;
      const int row_g = q0 + wave * 32 + rq;
      const float inv = 1.0f / lC[r];
      short* yp = y + (size_t)(b * T + row_g) * Cc + h * HD;
      yp[l32] = f2b(o0[r] * inv);
      yp[32 + l32] = f2b(o1[r] * inv);
    }
  }
}

extern "C" void kernel_launch(void* const* d_in, const int* in_sizes, int n_in,
                              void* d_out, int out_size, void* d_ws, size_t ws_size,
                              hipStream_t stream) {
  constexpr int B = 4, T = 2048, C = 1024;
  constexpr int M = B * T;          // 8192
  constexpr int N1 = 3 * C;         // 3072
  const float* x      = (const float*)d_in[0];
  const float* w_attn = (const float*)d_in[1];
  const float* w_proj = (const float*)d_in[2];
  float* out = (float*)d_out;

  char* ws = (char*)d_ws;
  short* xb   = (short*)(ws + 0);                       // 16 MB (x bf16)
  short* waT  = (short*)(ws + 16777216);                // 6 MB
  short* wpT  = (short*)(ws + 23068672);                // 2 MB
  short* qkb  = (short*)(ws + 25165824);                // 32 MB  [b*T+t][2048] = Q,K
  short* vT   = (short*)(ws + 58720256);                // 16 MB  [(b*16+h)*64+d][T]
  short* yb   = (short*)(ws + 75497472);                // 16 MB

  const float qscale = 0.125f * 1.44269504088896340736f;  // 1/sqrt(64) * log2(e)

  pre_kernel<<<12288, 256, 0, stream>>>(x, xb, w_attn, waT, w_proj, wpT, qscale);
  // qkv GEMM (VFUSE): 128x192 tile, 512 thr, 16 waves/CU -> 16x64 = 1024 blocks
  gemm_hi_kernel<192, short, true><<<dim3(N1 / 192, M / 128), 512, 0, stream>>>(
      xb, waT, qkb, vT, M, N1, C);
  // attn: R4-proven 4-wave 128-row qtile structure
  attn_kernel<<<dim3(8, B * 16), 256, 0, stream>>>(qkb, vT, yb);
  // proj: 128x128 tile -> 8x64 = 512 blocks
  gemm_hi_kernel<128, float, false><<<dim3(C / 128, M / 128), 512, 0, stream>>>(
      yb, wpT, out, nullptr, M, C, C);
}

// Round 8
// 215.048 us; speedup vs baseline: 1.0703x; 1.0703x over previous
//
#include <hip/hip_runtime.h>
#include <hip/hip_bf16.h>

typedef short bf16x8 __attribute__((ext_vector_type(8)));
typedef short short4v __attribute__((ext_vector_type(4)));
typedef float f32x4 __attribute__((ext_vector_type(4)));
typedef float f32x16 __attribute__((ext_vector_type(16)));

template <bool V> struct BoolC { static constexpr bool value = V; };

__device__ __forceinline__ short f2b(float f) {
  __hip_bfloat16 h = __float2bfloat16(f);
  union { __hip_bfloat16 h; short s; } u; u.h = h; return u.s;
}

// packed f32->bf16 pair (RNE), low = lo, high = hi
__device__ __forceinline__ unsigned cvtpk_bf16(float lo, float hi) {
  unsigned r;
  asm("v_cvt_pk_bf16_f32 %0, %1, %2" : "=v"(r) : "v"(lo), "v"(hi));
  return r;
}

__device__ __forceinline__ f32x16 mfma32(bf16x8 a, bf16x8 b, f32x16 c) {
  return __builtin_amdgcn_mfma_f32_32x32x16_bf16(a, b, c, 0, 0, 0);
}

template <int N> __device__ __forceinline__ void vmwait() {
  if constexpr (N == 0) asm volatile("s_waitcnt vmcnt(0)" ::: "memory");
  else if constexpr (N == 1) asm volatile("s_waitcnt vmcnt(1)" ::: "memory");
  else if constexpr (N == 2) asm volatile("s_waitcnt vmcnt(2)" ::: "memory");
  else if constexpr (N == 3) asm volatile("s_waitcnt vmcnt(3)" ::: "memory");
  else if constexpr (N == 4) asm volatile("s_waitcnt vmcnt(4)" ::: "memory");
  else if constexpr (N == 5) asm volatile("s_waitcnt vmcnt(5)" ::: "memory");
  else if constexpr (N == 6) asm volatile("s_waitcnt vmcnt(6)" ::: "memory");
  else if constexpr (N == 7) asm volatile("s_waitcnt vmcnt(7)" ::: "memory");
  else asm volatile("s_waitcnt vmcnt(8)" ::: "memory");
}

// async 16B global -> LDS DMA (lane i lands at lds_base + i*16; lds ptr wave-uniform)
__device__ __forceinline__ void async_copy16(const short* g, short* l) {
  __builtin_amdgcn_global_load_lds((const __attribute__((address_space(1))) void*)g,
                                   (__attribute__((address_space(3))) void*)l, 16, 0, 0);
}

// ---------------- fused preprocessing: x->bf16, w_attn^T (qscaled), w_proj^T ----------------
__global__ __launch_bounds__(256) void pre_kernel(const float* __restrict__ x, short* __restrict__ xb,
                                                  const float* __restrict__ wa, short* __restrict__ waT,
                                                  const float* __restrict__ wp, short* __restrict__ wpT,
                                                  float qscale) {
  const int tid = threadIdx.x;
  const int blk = blockIdx.x;
  if (blk < 8192) {
    const int i = blk * 256 + tid;
    const float4 v = ((const float4*)x)[i];
    short4v o;
    o[0] = f2b(v.x); o[1] = f2b(v.y); o[2] = f2b(v.z); o[3] = f2b(v.w);
    ((short4v*)xb)[i] = o;
    return;
  }
  __shared__ float t[32][33];
  const float* in; short* out;
  int idx, gxb, Cn, qrows; float qs;
  if (blk < 11264) { idx = blk - 8192;  in = wa; out = waT; gxb = 96; Cn = 3072; qrows = 1024; qs = qscale; }
  else             { idx = blk - 11264; in = wp; out = wpT; gxb = 32; Cn = 1024; qrows = 0;    qs = 1.0f; }
  const int bx = idx % gxb, by = idx / gxb;
  const int tx = tid & 31, ty = tid >> 5;
  const int c0 = bx * 32, r0 = by * 32;
#pragma unroll
  for (int yy = 0; yy < 32; yy += 8)
    t[ty + yy][tx] = in[(size_t)(r0 + ty + yy) * Cn + (c0 + tx)];
  __syncthreads();
#pragma unroll
  for (int yy = 0; yy < 32; yy += 8) {
    const int orow = c0 + ty + yy;
    float v = t[tx][ty + yy];
    if (orow < qrows) v *= qs;
    out[(size_t)orow * 1024 + (r0 + tx)] = f2b(v);
  }
}

// ---------------- C = A * Bt^T — 128xBN tile, 4-phase ledger, 2 blocks/CU ----------------
// (R6-proven best of 5 structural variants: 857 TF qkv, matches guide's m248 K=1024 ceiling.)
// VFUSE (qkv only): cols<2048 -> qk buffer [row][2048]; cols>=2048 -> V stored TRANSPOSED
// into vT[(b*16+h)*64+d][t] (aligned 8B stores; 2048 boundary 16-aligned -> uniform branch).
template <int BN, typename OutT, bool VFUSE>
__global__ __launch_bounds__(256, 2) void gemm2b_kernel(const short* __restrict__ A,
                                                        const short* __restrict__ Bt,
                                                        OutT* __restrict__ C,
                                                        short* __restrict__ vTo,
                                                        int M, int N, int K) {
  constexpr int NB = BN / 64;        // n-frags per wave
  constexpr int NBU = BN / 32;       // B stage units per tile per wave
  constexpr int NSTREAM = NBU + 4;   // + 4 A units
  __shared__ short ldsA[2][128 * 64];
  __shared__ short ldsB[2][BN * 64];

  const int tid = threadIdx.x;
  const int w = tid >> 6, lane = tid & 63;
  const int quad = lane >> 4, l16 = lane & 15;
  const int wn = w * (BN / 4);

  const int gx = gridDim.x;
  const int nwg = gx * gridDim.y;
  const int flat = blockIdx.y * gx + blockIdx.x;
  const int swz = (flat & 7) * (nwg >> 3) + (flat >> 3);
  const int bn = swz % gx, bm = swz / gx;
  const int m0 = bm * 128, n0 = bn * BN;

  const int rsub = lane >> 3;
  const int cl = (lane & 7) ^ rsub;
  const short* pAsrc = A + (size_t)(m0 + w * 8 + rsub) * K + cl * 8;
  const short* pBsrc = Bt + (size_t)(n0 + w * 8 + rsub) * K + cl * 8;

  f32x4 acc[8][NB] = {};
  bf16x8 bfr[NB][2];

  auto issue = [&](int i, int buf, int tt) {
    if (i < NBU)
      async_copy16(pBsrc + (size_t)(i * 32) * K + tt * 64, &ldsB[buf][(i * 32 + w * 8) * 64]);
    else
      async_copy16(pAsrc + (size_t)((i - NBU) * 32) * K + tt * 64,
                   &ldsA[buf][((i - NBU) * 32 + w * 8) * 64]);
  };
  auto readA = [&](bf16x8 (&af)[2][2], int buf, int P) {
#pragma unroll
    for (int mm = 0; mm < 2; ++mm)
#pragma unroll
      for (int kh = 0; kh < 2; ++kh)
        af[mm][kh] = *(const bf16x8*)&ldsA[buf][(P * 32 + mm * 16 + l16) * 64 +
                                                (((kh * 4 + quad) ^ (l16 & 7)) * 8)];
  };
  auto readB = [&](int buf) {
#pragma unroll
    for (int nf = 0; nf < NB; ++nf)
#pragma unroll
      for (int kh = 0; kh < 2; ++kh)
        bfr[nf][kh] = *(const bf16x8*)&ldsB[buf][(wn + nf * 16 + l16) * 64 +
                                                 (((kh * 4 + quad) ^ (l16 & 7)) * 8)];
  };

#define PHASE(P)                                                                               \
  {                                                                                            \
    constexpr int ISS0 = (NSTREAM + 3) >> 2, ISS1 = (NSTREAM + 2) >> 2,                        \
                  ISS2 = (NSTREAM + 1) >> 2;                                                   \
    constexpr int CUM = ((P) > 0 ? ISS0 : 0) + ((P) > 1 ? ISS1 : 0) + ((P) > 2 ? ISS2 : 0);    \
    constexpr int GS = NSTREAM - (NBU + 1 + (P)) + CUM;                                        \
    constexpr int GL = 3 - (P);                                                                \
    if constexpr ((P) == 0) asm volatile("s_waitcnt lgkmcnt(0)" ::: "memory");                 \
    if constexpr (LAST) vmwait<GL>(); else vmwait<GS>();                                       \
    __builtin_amdgcn_s_barrier();                                                              \
    bf16x8 af[2][2];                                                                           \
    readA(af, buf, (P));                                                                       \
    if constexpr ((P) == 0) readB(buf);                                                        \
    if constexpr (!LAST) {                                                                     \
      constexpr int NI = (NSTREAM + 3 - (P)) >> 2;                                             \
      _Pragma("unroll") for (int ii = 0; ii < NI; ++ii) issue(CUM + ii, buf ^ 1, t + 1);       \
    }                                                                                          \
    __builtin_amdgcn_s_setprio(1);                                                             \
    _Pragma("unroll") for (int mm = 0; mm < 2; ++mm)                                           \
    _Pragma("unroll") for (int nf = 0; nf < NB; ++nf) {                                        \
      acc[(P)*2 + mm][nf] = __builtin_amdgcn_mfma_f32_16x16x32_bf16(af[mm][0], bfr[nf][0],     \
                                                                    acc[(P)*2 + mm][nf], 0, 0, 0); \
      acc[(P)*2 + mm][nf] = __builtin_amdgcn_mfma_f32_16x16x32_bf16(af[mm][1], bfr[nf][1],     \
                                                                    acc[(P)*2 + mm][nf], 0, 0, 0); \
    }                                                                                          \
    __builtin_amdgcn_s_setprio(0);                                                             \
  }

#pragma unroll
  for (int i = 0; i < NSTREAM; ++i) issue(i, 0, 0);

  const int NT = K >> 6;
  auto tile = [&](int t, int buf, auto lastc) {
    constexpr bool LAST = decltype(lastc)::value;
    PHASE(0)
    PHASE(1)
    PHASE(2)
    PHASE(3)
  };
  for (int t = 0; t < NT - 1; ++t) tile(t, t & 1, BoolC<false>{});
  tile(NT - 1, (NT - 1) & 1, BoolC<true>{});
#undef PHASE

  (void)M;
#pragma unroll
  for (int mf = 0; mf < 8; ++mf)
#pragma unroll
    for (int nf = 0; nf < NB; ++nf) {
      const int col = n0 + wn + nf * 16 + l16;
      const int row0 = m0 + mf * 16 + quad * 4;
      if constexpr (VFUSE) {
        if (col < 2048) {  // Q,K -> qk buffer, row stride 2048 (wave-uniform branch)
#pragma unroll
          for (int r = 0; r < 4; ++r)
            C[(size_t)(row0 + r) * 2048 + col] = f2b(acc[mf][nf][r]);
        } else {           // V -> transposed vT[(b*16+h)*64+d][t], aligned 8B store
          const int dp = col - 2048;
          const int bh64 = ((row0 >> 11) * 16 + (dp >> 6)) * 64 + (dp & 63);
          const int t0 = row0 & 2047;
          short4v v4;
#pragma unroll
          for (int r = 0; r < 4; ++r) v4[r] = f2b(acc[mf][nf][r]);
          *(short4v*)&vTo[(size_t)bh64 * 2048 + t0] = v4;
        }
      } else {
#pragma unroll
        for (int r = 0; r < 4; ++r) {
          const int row = row0 + r;
          if constexpr (sizeof(OutT) == 4)
            C[(size_t)row * N + col] = acc[mf][nf][r];
          else
            C[(size_t)row * N + col] = f2b(acc[mf][nf][r]);
        }
      }
    }
}

// ---------------- causal flash attention: ONE 128-row qtile per block, 4 blocks/CU ----------------
// R6 inner loop byte-identical; residency fix only. Grid (16,64) = 1024 blocks (was 512 with
// qtile-pairing -> hard 2-blocks/CU cap; per-iter wall 4166 cyc vs ~1800 cyc real chain =
// co-stalled barrier cadences). Now 4 blocks/CU co-resident (32KB LDS, ~100 VGPR allow it);
// independent barrier domains overlap each other's DMA-drain + exp2 chains.
// Dispatch-order shaping: linear block id l -> qtile rank l>>6 (0 = LARGEST tile t=15),
// bh = l&63. First 64 dispatched blocks are every head's 32-iter long pole; short blocks
// backfill CU tails. Same-head blocks share K/V via L2/L3 (16 readers per bh).
// Inner loop: swapped QK^T (S^T = mfma32(K,Q), col=q=lane&31), in-register softmax via
// cvt_pk + permlane32_swap, fixed-base exp2, l via ones-MFMA, XOR-chunk-swizzled K/V LDS
// staged by global_load_lds DMA double-buffer. Waves skip fully-masked tiles (j>jd).
__global__ __launch_bounds__(256, 2) void attn_kernel(const short* __restrict__ qk,
                                                      const short* __restrict__ vT,
                                                      short* __restrict__ y) {
  constexpr int T = 2048, C2 = 2048, Cc = 1024, HD = 64;
  const int l = blockIdx.y * 16 + blockIdx.x;   // 0..1023, dispatch-ordered
  const int rank = l >> 6;                      // 0 (most work) .. 15 (least)
  const int bh = l & 63;
  const int t = 15 - rank;
  const int b = bh >> 4, h = bh & 15;
  const int tid = threadIdx.x, lane = tid & 63, wave = tid >> 6;
  const int l32 = lane & 31, hi = lane >> 5;

  __shared__ short Ksb[2][64 * 64];    // [buf][kv][d], XOR-swizzled 16B chunks
  __shared__ short Vtb[2][64 * 64];    // [buf][d][kv], XOR-swizzled 16B chunks

  const size_t base = (size_t)b * T * C2;
  const int qcol = h * HD, kcol = 1024 + h * HD;
  const size_t vtbase = (size_t)bh * HD * T;

  const int r8 = lane >> 3;
  const int cg8 = ((lane & 7) ^ r8) * 8;
  const short* gk[2];
  const short* gv[2];
  short* lk[2][2]; short* lv[2][2];
#pragma unroll
  for (int t8 = 0; t8 < 2; t8++) {
    const int row = wave * 16 + t8 * 8 + r8;
    gk[t8] = qk + base + (size_t)row * C2 + kcol + cg8;
    gv[t8] = vT + vtbase + (size_t)row * T + cg8;
#pragma unroll
    for (int bu = 0; bu < 2; bu++) {
      lk[bu][t8] = &Ksb[bu][(wave * 16 + t8 * 8) * 64];
      lv[bu][t8] = &Vtb[bu][(wave * 16 + t8 * 8) * 64];
    }
  }
  const int rs7 = l32 & 7;  // frag-read row parity for chunk XOR

  bf16x8 ones;
#pragma unroll
  for (int i = 0; i < 8; i++) ones[i] = (short)0x3F80;  // bf16 1.0

  const int q0 = t * 128;
  const int jmax = 2 * t + 1;
  const int jd = 2 * t + (wave >> 1);       // this wave's diagonal KV-tile
  const int qrow = q0 + wave * 32 + l32;    // this lane's q (S^T col)

  bf16x8 qf[4];
  {
    const short* qp = qk + base + (size_t)qrow * C2 + qcol + hi * 8;
#pragma unroll
    for (int wk = 0; wk < 4; wk++) qf[wk] = *(const bf16x8*)(qp + wk * 16);
  }

  f32x16 o0 = {}, o1 = {}, lC = {};

  async_copy16(gk[0], lk[0][0]);
  async_copy16(gk[1], lk[0][1]);
  async_copy16(gv[0], lv[0][0]);
  async_copy16(gv[1], lv[0][1]);

  for (int j = 0; j <= jmax; j++) {
    const int cur = j & 1;
    __syncthreads();  // drains vmcnt: tile j staged in buf[cur]

    if (j < jmax) {
      const size_t ko = (size_t)(j + 1) * 64 * C2;
      const int vo = (j + 1) * 64;
      async_copy16(gk[0] + ko, lk[cur ^ 1][0]);
      async_copy16(gk[1] + ko, lk[cur ^ 1][1]);
      async_copy16(gv[0] + vo, lv[cur ^ 1][0]);
      async_copy16(gv[1] + vo, lv[cur ^ 1][1]);
    }

    if (j > jd) continue;  // fully-masked tile for this wave (barriers above still uniform)

    const bool up = (64 * j + 32) <= (q0 + wave * 32 + 31);

    // ---- QK^T (swapped): st = K-tile x Q^T, col=q, row=kv ----
    f32x16 st0 = {}, st1 = {};
    __builtin_amdgcn_s_setprio(1);
#pragma unroll
    for (int wk = 0; wk < 4; wk++) {
      const bf16x8 k0 = *(const bf16x8*)&Ksb[cur][l32 * 64 + (((2 * wk + hi) ^ rs7) * 8)];
      st0 = mfma32(k0, qf[wk], st0);
    }
    if (up) {
#pragma unroll
      for (int wk = 0; wk < 4; wk++) {
        const bf16x8 k1 = *(const bf16x8*)&Ksb[cur][(32 + l32) * 64 + (((2 * wk + hi) ^ rs7) * 8)];
        st1 = mfma32(k1, qf[wk], st1);
      }
    }
    __builtin_amdgcn_s_setprio(0);

    // ---- causal mask on diagonal tile ----
    if (j == jd) {
#pragma unroll
      for (int r = 0; r < 16; r++) {
        const int kvl = 64 * j + (r & 3) + 8 * (r >> 2) + 4 * hi;
        if (kvl > qrow) st0[r] = -INFINITY;
        if (up && (kvl + 32 > qrow)) st1[r] = -INFINITY;
      }
    }

    // ---- V B-frags (kv-windows 0,1 always; 2,3 only if up) ----
    bf16x8 vf00, vf01, vf10, vf11, vf02, vf03, vf12, vf13;
    vf00 = *(const bf16x8*)&Vtb[cur][l32 * 64 + (((0 + hi) ^ rs7) * 8)];
    vf01 = *(const bf16x8*)&Vtb[cur][l32 * 64 + (((2 + hi) ^ rs7) * 8)];
    vf10 = *(const bf16x8*)&Vtb[cur][(32 + l32) * 64 + (((0 + hi) ^ rs7) * 8)];
    vf11 = *(const bf16x8*)&Vtb[cur][(32 + l32) * 64 + (((2 + hi) ^ rs7) * 8)];
    if (up) {
      vf02 = *(const bf16x8*)&Vtb[cur][l32 * 64 + (((4 + hi) ^ rs7) * 8)];
      vf03 = *(const bf16x8*)&Vtb[cur][l32 * 64 + (((6 + hi) ^ rs7) * 8)];
      vf12 = *(const bf16x8*)&Vtb[cur][(32 + l32) * 64 + (((4 + hi) ^ rs7) * 8)];
      vf13 = *(const bf16x8*)&Vtb[cur][(32 + l32) * 64 + (((6 + hi) ^ rs7) * 8)];
    }

    // ---- exp2 in-place, pack P->bf16 A-frags via cvt_pk + permlane32_swap ----
#pragma unroll
    for (int r = 0; r < 16; r++) st0[r] = __builtin_amdgcn_exp2f(st0[r]);
    bf16x8 pa0, pa1, pa2, pa3;
    {
      unsigned a0 = cvtpk_bf16(st0[0], st0[1]), c0 = cvtpk_bf16(st0[2], st0[3]);
      unsigned b0 = cvtpk_bf16(st0[4], st0[5]), d0 = cvtpk_bf16(st0[6], st0[7]);
      asm volatile("v_permlane32_swap_b32 %0, %1" : "+v"(a0), "+v"(b0));
      asm volatile("v_permlane32_swap_b32 %0, %1" : "+v"(c0), "+v"(d0));
      union { unsigned u[4]; bf16x8 v; } p; p.u[0] = a0; p.u[1] = c0; p.u[2] = b0; p.u[3] = d0;
      pa0 = p.v;
      unsigned a1 = cvtpk_bf16(st0[8], st0[9]), c1 = cvtpk_bf16(st0[10], st0[11]);
      unsigned b1 = cvtpk_bf16(st0[12], st0[13]), d1 = cvtpk_bf16(st0[14], st0[15]);
      asm volatile("v_permlane32_swap_b32 %0, %1" : "+v"(a1), "+v"(b1));
      asm volatile("v_permlane32_swap_b32 %0, %1" : "+v"(c1), "+v"(d1));
      union { unsigned u[4]; bf16x8 v; } q; q.u[0] = a1; q.u[1] = c1; q.u[2] = b1; q.u[3] = d1;
      pa1 = q.v;
    }
    if (up) {
#pragma unroll
      for (int r = 0; r < 16; r++) st1[r] = __builtin_amdgcn_exp2f(st1[r]);
      unsigned a2 = cvtpk_bf16(st1[0], st1[1]), c2 = cvtpk_bf16(st1[2], st1[3]);
      unsigned b2 = cvtpk_bf16(st1[4], st1[5]), d2 = cvtpk_bf16(st1[6], st1[7]);
      asm volatile("v_permlane32_swap_b32 %0, %1" : "+v"(a2), "+v"(b2));
      asm volatile("v_permlane32_swap_b32 %0, %1" : "+v"(c2), "+v"(d2));
      union { unsigned u[4]; bf16x8 v; } p; p.u[0] = a2; p.u[1] = c2; p.u[2] = b2; p.u[3] = d2;
      pa2 = p.v;
      unsigned a3 = cvtpk_bf16(st1[8], st1[9]), c3 = cvtpk_bf16(st1[10], st1[11]);
      unsigned b3 = cvtpk_bf16(st1[12], st1[13]), d3 = cvtpk_bf16(st1[14], st1[15]);
      asm volatile("v_permlane32_swap_b32 %0, %1" : "+v"(a3), "+v"(b3));
      asm volatile("v_permlane32_swap_b32 %0, %1" : "+v"(c3), "+v"(d3));
      union { unsigned u[4]; bf16x8 v; } q; q.u[0] = a3; q.u[1] = c3; q.u[2] = b3; q.u[3] = d3;
      pa3 = q.v;
    }

    // ---- l-sum (ones-MFMA, C-layout) + PV ----
    __builtin_amdgcn_s_setprio(1);
    lC = mfma32(pa0, ones, lC);
    lC = mfma32(pa1, ones, lC);
    o0 = mfma32(pa0, vf00, o0);
    o0 = mfma32(pa1, vf01, o0);
    o1 = mfma32(pa0, vf10, o1);
    o1 = mfma32(pa1, vf11, o1);
    if (up) {
      lC = mfma32(pa2, ones, lC);
      lC = mfma32(pa3, ones, lC);
      o0 = mfma32(pa2, vf02, o0);
      o0 = mfma32(pa3, vf03, o0);
      o1 = mfma32(pa2, vf12, o1);
      o1 = mfma32(pa3, vf13, o1);
    }
    __builtin_amdgcn_s_setprio(0);
  }

  // ---- epilogue: divide by l (same C-layout), store bf16 ----
#pragma unroll
  for (int r = 0; r < 16; r++) {
    const int rq = (r & 3) + 8 * (r >> 2) + 4 * hi;
    const int row_g = q0 + wave * 32 + rq;
    const float inv = 1.0f / lC[r];
    short* yp = y + (size_t)(b * T + row_g) * Cc + h * HD;
    yp[l32] = f2b(o0[r] * inv);
    yp[32 + l32] = f2b(o1[r] * inv);
  }
}

extern "C" void kernel_launch(void* const* d_in, const int* in_sizes, int n_in,
                              void* d_out, int out_size, void* d_ws, size_t ws_size,
                              hipStream_t stream) {
  constexpr int B = 4, T = 2048, C = 1024;
  constexpr int M = B * T;          // 8192
  constexpr int N1 = 3 * C;         // 3072
  const float* x      = (const float*)d_in[0];
  const float* w_attn = (const float*)d_in[1];
  const float* w_proj = (const float*)d_in[2];
  float* out = (float*)d_out;

  char* ws = (char*)d_ws;
  short* xb   = (short*)(ws + 0);                       // 16 MB (x bf16)
  short* waT  = (short*)(ws + 16777216);                // 6 MB
  short* wpT  = (short*)(ws + 23068672);                // 2 MB
  short* qkb  = (short*)(ws + 25165824);                // 32 MB  [b*T+t][2048] = Q,K
  short* vT   = (short*)(ws + 58720256);                // 16 MB  [(b*16+h)*64+d][T]
  short* yb   = (short*)(ws + 75497472);                // 16 MB

  const float qscale = 0.125f * 1.44269504088896340736f;  // 1/sqrt(64) * log2(e)

  pre_kernel<<<12288, 256, 0, stream>>>(x, xb, w_attn, waT, w_proj, wpT, qscale);
  // qkv GEMM (VFUSE, R6-proven): 128x192 tile -> 16x64 = 1024 blocks, 2 blocks/CU
  gemm2b_kernel<192, short, true><<<dim3(N1 / 192, M / 128), 256, 0, stream>>>(
      xb, waT, qkb, vT, M, N1, C);
  // attn: one qtile per block, work-descending dispatch, 1024 blocks -> 4 blocks/CU
  attn_kernel<<<dim3(16, 64), 256, 0, stream>>>(qkb, vT, yb);
  // proj: 128x128 tile -> 8x64 = 512 blocks, 2 blocks/CU
  gemm2b_kernel<128, float, false><<<dim3(C / 128, M / 128), 256, 0, stream>>>(
      yb, wpT, out, nullptr, M, C, C);
}